// Round 7
// baseline (272.240 us; speedup 1.0000x reference)
//
#include <hip/hip_runtime.h>
#include <hip/hip_bf16.h>
#include <stdint.h>

#define DI __device__ __forceinline__

typedef __bf16 bf16x8 __attribute__((ext_vector_type(8)));
typedef float f32x4 __attribute__((ext_vector_type(4)));
typedef unsigned short u16;

// ---------- helpers ----------
DI u16 f2bf(float f) {
  union { float f; uint32_t u; } x; x.f = f;
  uint32_t r = (x.u + 0x7FFFu + ((x.u >> 16) & 1u)) >> 16;
  return (u16)r;
}
DI bf16x8 load16(const u16* p) { return *(const bf16x8*)p; }

DI void async_copy16(void* lds, const void* g) {
  __builtin_amdgcn_global_load_lds(
      (const __attribute__((address_space(1))) uint32_t*)g,
      (__attribute__((address_space(3))) uint32_t*)lds, 16, 0, 0);
}

DI f32x4 mfma16(bf16x8 a, bf16x8 b, f32x4 c) {
  return __builtin_amdgcn_mfma_f32_16x16x32_bf16(a, b, c, 0, 0, 0);
}

// pack 2 floats -> 2 bf16 (one v_cvt_pk_bf16_f32)
DI uint32_t pk_bf16(float a, float b) {
  union { __hip_bfloat162 v; uint32_t u; } r;
  r.v = __float22bfloat162_rn(make_float2(a, b));
  return r.u;
}

// scale * log2(e), folded into Q at GEMM1 epilogue
#define QSCALE (0.125f * 1.44269504088896340736f)

// ---------- fused fp32 -> bf16 conversion of all three inputs ----------
__global__ __launch_bounds__(256)
void cvt_all(const float* __restrict__ s0, u16* __restrict__ d0, int n0,
             const float* __restrict__ s1, u16* __restrict__ d1, int n1,
             const float* __restrict__ s2, u16* __restrict__ d2, int n2) {
  int i = (blockIdx.x * 256 + threadIdx.x) * 4;
  const float* s; u16* d;
  if (i < n0) { s = s0 + i; d = d0 + i; }
  else if (i < n0 + n1) { s = s1 + (i - n0); d = d1 + (i - n0); }
  else if (i < n0 + n1 + n2) { s = s2 + (i - n0 - n1); d = d2 + (i - n0 - n1); }
  else return;
  float4 v = *(const float4*)s;
  ushort4 o;
  o.x = f2bf(v.x); o.y = f2bf(v.y); o.z = f2bf(v.z); o.w = f2bf(v.w);
  *(ushort4*)d = o;
}

// ---------- QKV GEMM with layout-specializing epilogue ----------
// A: x_bf16 [8192,768], B: w_qkv_bf16 [2304,768].
// n in [0,768)    -> Qb[m][n]      scaled by QSCALE
// n in [768,1536) -> Kb[m][n-768]
// n in [1536,2304)-> Vt[b][h][d][nseq]   (b=m>>11, nseq=m&2047)
__global__ __launch_bounds__(256)
void gemm_qkv(const u16* __restrict__ A, const u16* __restrict__ Bm,
              u16* __restrict__ Qb, u16* __restrict__ Kb, u16* __restrict__ Vt,
              int M, int N, int K) {
  __shared__ u16 As[128 * 32];
  __shared__ u16 Bs[128 * 32];

  const int tid  = threadIdx.x;
  const int lane = tid & 63;
  const int wave = tid >> 6;
  const int m0 = blockIdx.y * 128;
  const int n0 = blockIdx.x * 128;
  const int wm = (wave & 1) * 64;
  const int wn = (wave >> 1) * 64;
  const int c = lane & 15;
  const int g = lane >> 4;

  f32x4 acc[4][4] = {};

  for (int k0 = 0; k0 < K; k0 += 32) {
#pragma unroll
    for (int i = 0; i < 2; ++i) {
      int j = i * 256 + tid;
      int row = j >> 2;
      int col = (j & 3) * 8;
      async_copy16(&As[j * 8], &A[(size_t)(m0 + row) * K + k0 + col]);
      async_copy16(&Bs[j * 8], &Bm[(size_t)(n0 + row) * K + k0 + col]);
    }
    __syncthreads();

    bf16x8 af[4], bfr[4];
#pragma unroll
    for (int t = 0; t < 4; ++t) {
      af[t]  = *(const bf16x8*)&As[(wm + t * 16 + c) * 32 + g * 8];
      bfr[t] = *(const bf16x8*)&Bs[(wn + t * 16 + c) * 32 + g * 8];
    }
#pragma unroll
    for (int mt = 0; mt < 4; ++mt)
#pragma unroll
      for (int nt = 0; nt < 4; ++nt)
        acc[mt][nt] = mfma16(af[mt], bfr[nt], acc[mt][nt]);
    __syncthreads();
  }

  // epilogue (block-uniform branch: 768 % 128 == 0)
  if (n0 < 768) {            // Q, pre-scaled
#pragma unroll
    for (int nt = 0; nt < 4; ++nt) {
      int col = n0 + wn + nt * 16 + c;
#pragma unroll
      for (int mt = 0; mt < 4; ++mt)
#pragma unroll
        for (int r = 0; r < 4; ++r) {
          int row = m0 + wm + mt * 16 + g * 4 + r;
          Qb[(size_t)row * 768 + col] = f2bf(acc[mt][nt][r] * QSCALE);
        }
    }
  } else if (n0 < 1536) {    // K
#pragma unroll
    for (int nt = 0; nt < 4; ++nt) {
      int col = n0 - 768 + wn + nt * 16 + c;
#pragma unroll
      for (int mt = 0; mt < 4; ++mt)
#pragma unroll
        for (int r = 0; r < 4; ++r) {
          int row = m0 + wm + mt * 16 + g * 4 + r;
          Kb[(size_t)row * 768 + col] = f2bf(acc[mt][nt][r]);
        }
    }
  } else {                   // V transposed: Vt[((b*12+h)*64+d)*2048 + nseq]
#pragma unroll
    for (int nt = 0; nt < 4; ++nt) {
      int cv = n0 - 1536 + wn + nt * 16 + c;
      int hv = cv >> 6, d = cv & 63;
#pragma unroll
      for (int mt = 0; mt < 4; ++mt) {
        int row = m0 + wm + mt * 16 + g * 4;  // 4 consecutive rows
        int b = row >> 11, nn = row & 2047;
        ushort4 o;
        o.x = f2bf(acc[mt][nt][0]); o.y = f2bf(acc[mt][nt][1]);
        o.z = f2bf(acc[mt][nt][2]); o.w = f2bf(acc[mt][nt][3]);
        *(ushort4*)&Vt[(((size_t)b * 12 + hv) * 64 + d) * 2048 + nn] = o;
      }
    }
  }
}

// ---------- GEMM2: out[m,n] = sum_k A[m,k] B[n,k] + bias[n], fp32 out ----------
__global__ __launch_bounds__(256)
void gemm_proj(const u16* __restrict__ A, const u16* __restrict__ Bm,
               const float* __restrict__ bias, float* __restrict__ Co,
               int M, int N, int K) {
  __shared__ u16 As[128 * 32];
  __shared__ u16 Bs[128 * 32];

  const int tid  = threadIdx.x;
  const int lane = tid & 63;
  const int wave = tid >> 6;
  const int m0 = blockIdx.y * 128;
  const int n0 = blockIdx.x * 128;
  const int wm = (wave & 1) * 64;
  const int wn = (wave >> 1) * 64;
  const int c = lane & 15;
  const int g = lane >> 4;

  f32x4 acc[4][4] = {};

  for (int k0 = 0; k0 < K; k0 += 32) {
#pragma unroll
    for (int i = 0; i < 2; ++i) {
      int j = i * 256 + tid;
      int row = j >> 2;
      int col = (j & 3) * 8;
      async_copy16(&As[j * 8], &A[(size_t)(m0 + row) * K + k0 + col]);
      async_copy16(&Bs[j * 8], &Bm[(size_t)(n0 + row) * K + k0 + col]);
    }
    __syncthreads();

    bf16x8 af[4], bfr[4];
#pragma unroll
    for (int t = 0; t < 4; ++t) {
      af[t]  = *(const bf16x8*)&As[(wm + t * 16 + c) * 32 + g * 8];
      bfr[t] = *(const bf16x8*)&Bs[(wn + t * 16 + c) * 32 + g * 8];
    }
#pragma unroll
    for (int mt = 0; mt < 4; ++mt)
#pragma unroll
      for (int nt = 0; nt < 4; ++nt)
        acc[mt][nt] = mfma16(af[mt], bfr[nt], acc[mt][nt]);
    __syncthreads();
  }

#pragma unroll
  for (int nt = 0; nt < 4; ++nt) {
    int col = n0 + wn + nt * 16 + c;
    float bv = bias[col];
#pragma unroll
    for (int mt = 0; mt < 4; ++mt)
#pragma unroll
      for (int r = 0; r < 4; ++r) {
        int row = m0 + wm + mt * 16 + g * 4 + r;
        Co[(size_t)row * N + col] = acc[mt][nt][r] + bv;
      }
  }
}

// ---------- Flash attention v6: q=64/wave, K-step 32, bank-clean P ----------
// Transposed chain: S^T = K*Q^T (k in-lane -> b64 P writes), O^T = V^T*P^T
// (d in-lane epilogue), row sums via ones-MFMA (in-lane normalize).
// P layout: per subtile 16 rows(q=c) x stride 36 u16 (18 dw; 18c mod 32 is a
// permutation of 16 values -> bank-clean for c-major access, 8B-aligned b64).
// Block = 128 threads (2 waves); wave owns 64 q-rows; grid = 4*12*(2048/128)
// = 768 = exactly 3 blocks/CU (balanced).
__global__ __launch_bounds__(128)
void attn_flash(const u16* __restrict__ Qb, const u16* __restrict__ Kb,
                const u16* __restrict__ Vt, u16* __restrict__ out) {
  __shared__ u16 Ks[2 * 32 * 32];                    // [half][kk][32e]  4 KB
  __shared__ u16 Vs[64 * 32];                        // [d][ke]          4 KB
  __shared__ __align__(16) u16 Plds[2][4 * 16 * 36]; // per wave/sub    9 KB

  const int tid  = threadIdx.x;
  const int lane = tid & 63;
  const int wave = tid >> 6;
  const int idx = blockIdx.x;
  const int qchunk = idx & 15;        // 2048/128 = 16
  const int h = (idx >> 4) % 12;
  const int b = idx / (16 * 12);
  const int q0 = qchunk * 128 + wave * 64;
  const int c = lane & 15;
  const int g = lane >> 4;

  const u16* Qp = Qb + (size_t)b * 2048 * 768 + h * 64;   // row stride 768
  const u16* Kp = Kb + (size_t)b * 2048 * 768 + h * 64;
  const u16* Vp = Vt + ((size_t)b * 12 + h) * 64 * 2048;  // [d][nseq]

  u16* pw = &Plds[wave][0];

  // Q as B-operand: per subtile s (16 q-rows), two d-halves
  bf16x8 qf[4][2];
#pragma unroll
  for (int s = 0; s < 4; ++s) {
    qf[s][0] = load16(&Qp[(size_t)(q0 + s * 16 + c) * 768 + g * 8]);
    qf[s][1] = load16(&Qp[(size_t)(q0 + s * 16 + c) * 768 + 32 + g * 8]);
  }

  bf16x8 ones;
#pragma unroll
  for (int j = 0; j < 8; ++j) ones[j] = (__bf16)1.0f;

  // staging decode: two 16B chunks per thread for each of Ks, Vs
  const int ja = tid, jb = tid + 128;

  f32x4 o[4][4] = {};   // [dt][s]  O^T frags: row d, col q
  f32x4 osum[4] = {};   // ones-MFMA row-sums, col q

  for (int k0 = 0; k0 < 2048; k0 += 32) {
    // ---- stage K (32k x 64d) and V^T (64d x 32k): 8 KB, 4 insts/thread ----
    {
      int ha = ja >> 7, ra = ja & 127, ka = ra >> 2, ea = (ra & 3) * 8;
      int hb = jb >> 7, rb = jb & 127, kb = rb >> 2, eb = (rb & 3) * 8;
      async_copy16(&Ks[ja * 8], &Kp[(size_t)(k0 + ka) * 768 + ha * 32 + ea]);
      async_copy16(&Ks[jb * 8], &Kp[(size_t)(k0 + kb) * 768 + hb * 32 + eb]);
      int da = ja >> 2, fa = (ja & 3) * 8;
      int db = jb >> 2, fb = (jb & 3) * 8;
      async_copy16(&Vs[ja * 8], &Vp[(size_t)da * 2048 + k0 + fa]);
      async_copy16(&Vs[jb * 8], &Vp[(size_t)db * 2048 + k0 + fb]);
    }
    __syncthreads();

    // ---- S^T = K·Q^T; P = exp2(S); b64 writes, 4 k per lane ----
#pragma unroll
    for (int kt = 0; kt < 2; ++kt) {
      bf16x8 kf0 = *(const bf16x8*)&Ks[(kt * 16 + c) * 32 + g * 8];
      bf16x8 kf1 = *(const bf16x8*)&Ks[1024 + (kt * 16 + c) * 32 + g * 8];
#pragma unroll
      for (int s = 0; s < 4; ++s) {
        f32x4 z = {};
        f32x4 st = mfma16(kf0, qf[s][0], z);
        st = mfma16(kf1, qf[s][1], st);
        float p0 = __builtin_amdgcn_exp2f(st[0]);
        float p1 = __builtin_amdgcn_exp2f(st[1]);
        float p2 = __builtin_amdgcn_exp2f(st[2]);
        float p3 = __builtin_amdgcn_exp2f(st[3]);
        *(uint2*)&pw[s * 576 + c * 36 + kt * 16 + g * 4] =
            make_uint2(pk_bf16(p0, p1), pk_bf16(p2, p3));
      }
    }
    __asm__ volatile("s_waitcnt lgkmcnt(0)" ::: "memory");

    // ---- PV: pf = P[q=c][g*8..+7] (2x b64), vf shared across subtiles ----
    bf16x8 pf[4];
#pragma unroll
    for (int s = 0; s < 4; ++s) {
      union { uint2 u2[2]; bf16x8 v; } u;
      u.u2[0] = *(const uint2*)&pw[s * 576 + c * 36 + g * 8];
      u.u2[1] = *(const uint2*)&pw[s * 576 + c * 36 + g * 8 + 4];
      pf[s] = u.v;
      osum[s] = mfma16(ones, pf[s], osum[s]);
    }
#pragma unroll
    for (int dt = 0; dt < 4; ++dt) {
      bf16x8 vf = *(const bf16x8*)&Vs[(dt * 16 + c) * 32 + g * 8];
#pragma unroll
      for (int s = 0; s < 4; ++s)
        o[dt][s] = mfma16(vf, pf[s], o[dt][s]);
    }
    __syncthreads();
  }

  // ---- epilogue: in-lane normalize; O^T value (d = dt*16+g*4+r, q = c) ----
#pragma unroll
  for (int s = 0; s < 4; ++s) {
    float inv = 1.f / osum[s][0];
#pragma unroll
    for (int dt = 0; dt < 4; ++dt) {
      uint2 w = make_uint2(pk_bf16(o[dt][s][0] * inv, o[dt][s][1] * inv),
                           pk_bf16(o[dt][s][2] * inv, o[dt][s][3] * inv));
      *(uint2*)&out[(size_t)(b * 2048 + q0 + s * 16 + c) * 768 +
                    h * 64 + dt * 16 + g * 4] = w;
    }
  }
}

// ---------- launcher ----------
extern "C" void kernel_launch(void* const* d_in, const int* in_sizes, int n_in,
                              void* d_out, int out_size, void* d_ws, size_t ws_size,
                              hipStream_t stream) {
  const float* x      = (const float*)d_in[0];  // [4,2048,768] fp32
  const float* w_qkv  = (const float*)d_in[1];  // [2304,768]
  const float* w_proj = (const float*)d_in[2];  // [768,768]
  const float* b_proj = (const float*)d_in[3];  // [768]
  float* out = (float*)d_out;                   // [4,2048,768] fp32

  const int M = 8192;     // B*N
  const int C = 768;
  const int NQKV = 2304;

  // workspace layout (bf16 elements) — total ~33.8M u16 = 67.7 MB
  u16* xb     = (u16*)d_ws;                        // 8192*768
  u16* wqkvb  = xb + (size_t)M * C;                // 2304*768
  u16* wprojb = wqkvb + (size_t)NQKV * C;          // 768*768
  u16* Qb     = wprojb + (size_t)C * C;            // 8192*768
  u16* Kb     = Qb + (size_t)M * C;                // 8192*768
  u16* Vt     = Kb + (size_t)M * C;                // 4*12*64*2048
  u16* attn   = Vt + (size_t)M * C;                // 8192*768

  dim3 blk(256);
  // 0) convert all fp32 inputs to bf16 in one launch
  const int n0 = M * C, n1 = NQKV * C, n2 = C * C;
  cvt_all<<<dim3((n0 + n1 + n2) / 1024), blk, 0, stream>>>(
      x, xb, n0, w_qkv, wqkvb, n1, w_proj, wprojb, n2);

  // 1) qkv GEMM with Q-scale / K / V-transpose epilogue
  gemm_qkv<<<dim3(NQKV / 128, M / 128), blk, 0, stream>>>(
      xb, wqkvb, Qb, Kb, Vt, M, NQKV, C);
  // 2) flash attention: 128-thread blocks, grid 768 (= 3 blocks/CU balanced)
  attn_flash<<<dim3(4 * 12 * 16), dim3(128), 0, stream>>>(Qb, Kb, Vt, attn);
  // 3) out = attn @ w_proj^T + b  (fp32 out)
  gemm_proj<<<dim3(C / 128, M / 128), blk, 0, stream>>>(
      attn, wprojb, b_proj, out, M, C, C);
}

// Round 8
// 237.230 us; speedup vs baseline: 1.1476x; 1.1476x over previous
//
#include <hip/hip_runtime.h>
#include <hip/hip_bf16.h>
#include <stdint.h>

#define DI __device__ __forceinline__

typedef __bf16 bf16x8 __attribute__((ext_vector_type(8)));
typedef float f32x4 __attribute__((ext_vector_type(4)));
typedef unsigned short u16;

// ---------- helpers ----------
DI u16 f2bf(float f) {
  union { float f; uint32_t u; } x; x.f = f;
  uint32_t r = (x.u + 0x7FFFu + ((x.u >> 16) & 1u)) >> 16;
  return (u16)r;
}
DI bf16x8 load16(const u16* p) { return *(const bf16x8*)p; }

DI void async_copy16(void* lds, const void* g) {
  __builtin_amdgcn_global_load_lds(
      (const __attribute__((address_space(1))) uint32_t*)g,
      (__attribute__((address_space(3))) uint32_t*)lds, 16, 0, 0);
}

DI f32x4 mfma16(bf16x8 a, bf16x8 b, f32x4 c) {
  return __builtin_amdgcn_mfma_f32_16x16x32_bf16(a, b, c, 0, 0, 0);
}

// pack 2 floats -> 2 bf16 (one v_cvt_pk_bf16_f32)
DI uint32_t pk_bf16(float a, float b) {
  union { __hip_bfloat162 v; uint32_t u; } r;
  r.v = __float22bfloat162_rn(make_float2(a, b));
  return r.u;
}

// scale * log2(e), folded into Q at GEMM1 epilogue
#define QSCALE (0.125f * 1.44269504088896340736f)

// ---------- fused fp32 -> bf16 conversion of all three inputs ----------
__global__ __launch_bounds__(256)
void cvt_all(const float* __restrict__ s0, u16* __restrict__ d0, int n0,
             const float* __restrict__ s1, u16* __restrict__ d1, int n1,
             const float* __restrict__ s2, u16* __restrict__ d2, int n2) {
  int i = (blockIdx.x * 256 + threadIdx.x) * 4;
  const float* s; u16* d;
  if (i < n0) { s = s0 + i; d = d0 + i; }
  else if (i < n0 + n1) { s = s1 + (i - n0); d = d1 + (i - n0); }
  else if (i < n0 + n1 + n2) { s = s2 + (i - n0 - n1); d = d2 + (i - n0 - n1); }
  else return;
  float4 v = *(const float4*)s;
  ushort4 o;
  o.x = f2bf(v.x); o.y = f2bf(v.y); o.z = f2bf(v.z); o.w = f2bf(v.w);
  *(ushort4*)d = o;
}

// ---------- QKV GEMM with layout-specializing epilogue ----------
// A: x_bf16 [8192,768], B: w_qkv_bf16 [2304,768].
// n in [0,768)    -> Qb[m][n]      scaled by QSCALE
// n in [768,1536) -> Kb[m][n-768]
// n in [1536,2304)-> Vt[b][h][d][nseq]   (b=m>>11, nseq=m&2047)
__global__ __launch_bounds__(256)
void gemm_qkv(const u16* __restrict__ A, const u16* __restrict__ Bm,
              u16* __restrict__ Qb, u16* __restrict__ Kb, u16* __restrict__ Vt,
              int M, int N, int K) {
  __shared__ u16 As[128 * 32];
  __shared__ u16 Bs[128 * 32];

  const int tid  = threadIdx.x;
  const int lane = tid & 63;
  const int wave = tid >> 6;
  const int m0 = blockIdx.y * 128;
  const int n0 = blockIdx.x * 128;
  const int wm = (wave & 1) * 64;
  const int wn = (wave >> 1) * 64;
  const int c = lane & 15;
  const int g = lane >> 4;

  f32x4 acc[4][4] = {};

  for (int k0 = 0; k0 < K; k0 += 32) {
#pragma unroll
    for (int i = 0; i < 2; ++i) {
      int j = i * 256 + tid;
      int row = j >> 2;
      int col = (j & 3) * 8;
      async_copy16(&As[j * 8], &A[(size_t)(m0 + row) * K + k0 + col]);
      async_copy16(&Bs[j * 8], &Bm[(size_t)(n0 + row) * K + k0 + col]);
    }
    __syncthreads();

    bf16x8 af[4], bfr[4];
#pragma unroll
    for (int t = 0; t < 4; ++t) {
      af[t]  = *(const bf16x8*)&As[(wm + t * 16 + c) * 32 + g * 8];
      bfr[t] = *(const bf16x8*)&Bs[(wn + t * 16 + c) * 32 + g * 8];
    }
#pragma unroll
    for (int mt = 0; mt < 4; ++mt)
#pragma unroll
      for (int nt = 0; nt < 4; ++nt)
        acc[mt][nt] = mfma16(af[mt], bfr[nt], acc[mt][nt]);
    __syncthreads();
  }

  // epilogue (block-uniform branch: 768 % 128 == 0)
  if (n0 < 768) {            // Q, pre-scaled
#pragma unroll
    for (int nt = 0; nt < 4; ++nt) {
      int col = n0 + wn + nt * 16 + c;
#pragma unroll
      for (int mt = 0; mt < 4; ++mt)
#pragma unroll
        for (int r = 0; r < 4; ++r) {
          int row = m0 + wm + mt * 16 + g * 4 + r;
          Qb[(size_t)row * 768 + col] = f2bf(acc[mt][nt][r] * QSCALE);
        }
    }
  } else if (n0 < 1536) {    // K
#pragma unroll
    for (int nt = 0; nt < 4; ++nt) {
      int col = n0 - 768 + wn + nt * 16 + c;
#pragma unroll
      for (int mt = 0; mt < 4; ++mt)
#pragma unroll
        for (int r = 0; r < 4; ++r) {
          int row = m0 + wm + mt * 16 + g * 4 + r;
          Kb[(size_t)row * 768 + col] = f2bf(acc[mt][nt][r]);
        }
    }
  } else {                   // V transposed: Vt[((b*12+h)*64+d)*2048 + nseq]
#pragma unroll
    for (int nt = 0; nt < 4; ++nt) {
      int cv = n0 - 1536 + wn + nt * 16 + c;
      int hv = cv >> 6, d = cv & 63;
#pragma unroll
      for (int mt = 0; mt < 4; ++mt) {
        int row = m0 + wm + mt * 16 + g * 4;  // 4 consecutive rows
        int b = row >> 11, nn = row & 2047;
        ushort4 o;
        o.x = f2bf(acc[mt][nt][0]); o.y = f2bf(acc[mt][nt][1]);
        o.z = f2bf(acc[mt][nt][2]); o.w = f2bf(acc[mt][nt][3]);
        *(ushort4*)&Vt[(((size_t)b * 12 + hv) * 64 + d) * 2048 + nn] = o;
      }
    }
  }
}

// ---------- GEMM2: out[m,n] = sum_k A[m,k] B[n,k] + bias[n], fp32 out ----------
__global__ __launch_bounds__(256)
void gemm_proj(const u16* __restrict__ A, const u16* __restrict__ Bm,
               const float* __restrict__ bias, float* __restrict__ Co,
               int M, int N, int K) {
  __shared__ u16 As[128 * 32];
  __shared__ u16 Bs[128 * 32];

  const int tid  = threadIdx.x;
  const int lane = tid & 63;
  const int wave = tid >> 6;
  const int m0 = blockIdx.y * 128;
  const int n0 = blockIdx.x * 128;
  const int wm = (wave & 1) * 64;
  const int wn = (wave >> 1) * 64;
  const int c = lane & 15;
  const int g = lane >> 4;

  f32x4 acc[4][4] = {};

  for (int k0 = 0; k0 < K; k0 += 32) {
#pragma unroll
    for (int i = 0; i < 2; ++i) {
      int j = i * 256 + tid;
      int row = j >> 2;
      int col = (j & 3) * 8;
      async_copy16(&As[j * 8], &A[(size_t)(m0 + row) * K + k0 + col]);
      async_copy16(&Bs[j * 8], &Bm[(size_t)(n0 + row) * K + k0 + col]);
    }
    __syncthreads();

    bf16x8 af[4], bfr[4];
#pragma unroll
    for (int t = 0; t < 4; ++t) {
      af[t]  = *(const bf16x8*)&As[(wm + t * 16 + c) * 32 + g * 8];
      bfr[t] = *(const bf16x8*)&Bs[(wn + t * 16 + c) * 32 + g * 8];
    }
#pragma unroll
    for (int mt = 0; mt < 4; ++mt)
#pragma unroll
      for (int nt = 0; nt < 4; ++nt)
        acc[mt][nt] = mfma16(af[mt], bfr[nt], acc[mt][nt]);
    __syncthreads();
  }

#pragma unroll
  for (int nt = 0; nt < 4; ++nt) {
    int col = n0 + wn + nt * 16 + c;
    float bv = bias[col];
#pragma unroll
    for (int mt = 0; mt < 4; ++mt)
#pragma unroll
      for (int r = 0; r < 4; ++r) {
        int row = m0 + wm + mt * 16 + g * 4 + r;
        Co[(size_t)row * N + col] = acc[mt][nt][r] + bv;
      }
  }
}

// ---------- Flash attention v7 ----------
// Round 5 shape (256T / 4 waves / q=32 per wave / K-step 64 / grid 768 =
// 3 blocks/CU = 12 waves/CU, balanced) + round 7 transposed chain:
//   S^T = K*Q^T  (k in-lane -> b64 P writes)
//   O^T = V^T*P^T (d in-lane -> b64 epilogue stores)
//   row sums via ones-MFMA (in-lane normalize, no shuffles)
// P layout: per wave/subtile, 16 rows (q=c) x stride 68 u16 (64 k + 4 pad).
// All LDS ops at their bank-minimum (b64: 4 clk, b128: 8 clk).
__global__ __launch_bounds__(256)
void attn_flash(const u16* __restrict__ Qb, const u16* __restrict__ Kb,
                const u16* __restrict__ Vt, u16* __restrict__ out) {
  __shared__ u16 Ks[2 * 64 * 32];                    // [half][kk][32e]  8 KB
  __shared__ u16 Vs[2 * 64 * 32];                    // [kt2][d][32e]    8 KB
  __shared__ __align__(16) u16 Plds[4][2 * 16 * 68]; // [wave][sub]   17.4 KB

  const int tid  = threadIdx.x;
  const int lane = tid & 63;
  const int wave = tid >> 6;
  const int idx = blockIdx.x;
  const int qchunk = idx & 15;        // N/128 = 16
  const int h = (idx >> 4) % 12;
  const int b = idx / (16 * 12);
  const int q0 = qchunk * 128 + wave * 32;
  const int c = lane & 15;
  const int g = lane >> 4;

  const u16* Qp = Qb + (size_t)b * 2048 * 768 + h * 64;   // row stride 768
  const u16* Kp = Kb + (size_t)b * 2048 * 768 + h * 64;
  const u16* Vp = Vt + ((size_t)b * 12 + h) * 64 * 2048;  // [d][nseq]

  u16* pw = &Plds[wave][0];

  // Q as B-operand: two q sub-tiles (16 rows each), two d-halves
  bf16x8 qf[2][2];
#pragma unroll
  for (int s = 0; s < 2; ++s) {
    qf[s][0] = load16(&Qp[(size_t)(q0 + s * 16 + c) * 768 + g * 8]);
    qf[s][1] = load16(&Qp[(size_t)(q0 + s * 16 + c) * 768 + 32 + g * 8]);
  }

  bf16x8 ones;
#pragma unroll
  for (int j = 0; j < 8; ++j) ones[j] = (__bf16)1.0f;

  const int j0 = tid, j1 = tid + 256;

  f32x4 o[4][2] = {};   // [dt][s]  O^T frags: row d, col q
  f32x4 osum[2] = {};   // ones-MFMA row-sums, col q

  for (int k0 = 0; k0 < 2048; k0 += 64) {
    // ---- stage K (64k x 64d) and V^T (64d x 64k): 16 KB, 4 insts/thread ----
    {
      int kk0 = (j0 >> 2) & 63, ch0 = j0 & 3;
      int kk1 = (j1 >> 2) & 63, ch1 = j1 & 3;
      async_copy16(&Ks[j0 * 8], &Kp[(size_t)(k0 + kk0) * 768 + ch0 * 8]);
      async_copy16(&Ks[j1 * 8], &Kp[(size_t)(k0 + kk1) * 768 + 32 + ch1 * 8]);
      async_copy16(&Vs[j0 * 8], &Vp[(size_t)kk0 * 2048 + k0 + ch0 * 8]);
      async_copy16(&Vs[j1 * 8], &Vp[(size_t)kk1 * 2048 + k0 + 32 + ch1 * 8]);
    }
    __syncthreads();

    // ---- S^T = K·Q^T per kt; P = exp2(S); one b64 write per (kt, sub) ----
#pragma unroll
    for (int kt = 0; kt < 4; ++kt) {
      bf16x8 kf0 = *(const bf16x8*)&Ks[(kt * 16 + c) * 32 + g * 8];
      bf16x8 kf1 = *(const bf16x8*)&Ks[64 * 32 + (kt * 16 + c) * 32 + g * 8];
#pragma unroll
      for (int s = 0; s < 2; ++s) {
        f32x4 z = {};
        f32x4 st = mfma16(kf0, qf[s][0], z);
        st = mfma16(kf1, qf[s][1], st);
        float p0 = __builtin_amdgcn_exp2f(st[0]);
        float p1 = __builtin_amdgcn_exp2f(st[1]);
        float p2 = __builtin_amdgcn_exp2f(st[2]);
        float p3 = __builtin_amdgcn_exp2f(st[3]);
        // row q=c (stride 68), element index within row = k = kt*16 + g*4
        *(uint2*)&pw[s * 1088 + c * 68 + kt * 16 + g * 4] =
            make_uint2(pk_bf16(p0, p1), pk_bf16(p2, p3));
      }
    }
    __asm__ volatile("s_waitcnt lgkmcnt(0)" ::: "memory");

    // ---- PV: pf[s][kt2] = P[q=c][kt2*32 + g*8 ..] (2x b64 each) ----
#pragma unroll
    for (int kt2 = 0; kt2 < 2; ++kt2) {
      bf16x8 pf[2];
#pragma unroll
      for (int s = 0; s < 2; ++s) {
        union { uint2 u2[2]; bf16x8 v; } u;
        u.u2[0] = *(const uint2*)&pw[s * 1088 + c * 68 + kt2 * 32 + g * 8];
        u.u2[1] = *(const uint2*)&pw[s * 1088 + c * 68 + kt2 * 32 + g * 8 + 4];
        pf[s] = u.v;
        osum[s] = mfma16(ones, pf[s], osum[s]);
      }
#pragma unroll
      for (int dt = 0; dt < 4; ++dt) {
        bf16x8 vf = *(const bf16x8*)&Vs[kt2 * 64 * 32 + (dt * 16 + c) * 32 + g * 8];
#pragma unroll
        for (int s = 0; s < 2; ++s)
          o[dt][s] = mfma16(vf, pf[s], o[dt][s]);
      }
    }
    __syncthreads();
  }

  // ---- epilogue: in-lane normalize; O^T value (d = dt*16+g*4+r, q = c) ----
#pragma unroll
  for (int s = 0; s < 2; ++s) {
    float inv = 1.f / osum[s][0];
#pragma unroll
    for (int dt = 0; dt < 4; ++dt) {
      uint2 w = make_uint2(pk_bf16(o[dt][s][0] * inv, o[dt][s][1] * inv),
                           pk_bf16(o[dt][s][2] * inv, o[dt][s][3] * inv));
      *(uint2*)&out[(size_t)(b * 2048 + q0 + s * 16 + c) * 768 +
                    h * 64 + dt * 16 + g * 4] = w;
    }
  }
}

// ---------- launcher ----------
extern "C" void kernel_launch(void* const* d_in, const int* in_sizes, int n_in,
                              void* d_out, int out_size, void* d_ws, size_t ws_size,
                              hipStream_t stream) {
  const float* x      = (const float*)d_in[0];  // [4,2048,768] fp32
  const float* w_qkv  = (const float*)d_in[1];  // [2304,768]
  const float* w_proj = (const float*)d_in[2];  // [768,768]
  const float* b_proj = (const float*)d_in[3];  // [768]
  float* out = (float*)d_out;                   // [4,2048,768] fp32

  const int M = 8192;     // B*N
  const int C = 768;
  const int NQKV = 2304;

  // workspace layout (bf16 elements) — total ~33.8M u16 = 67.7 MB
  u16* xb     = (u16*)d_ws;                        // 8192*768
  u16* wqkvb  = xb + (size_t)M * C;                // 2304*768
  u16* wprojb = wqkvb + (size_t)NQKV * C;          // 768*768
  u16* Qb     = wprojb + (size_t)C * C;            // 8192*768
  u16* Kb     = Qb + (size_t)M * C;                // 8192*768
  u16* Vt     = Kb + (size_t)M * C;                // 4*12*64*2048
  u16* attn   = Vt + (size_t)M * C;                // 8192*768

  dim3 blk(256);
  // 0) convert all fp32 inputs to bf16 in one launch
  const int n0 = M * C, n1 = NQKV * C, n2 = C * C;
  cvt_all<<<dim3((n0 + n1 + n2) / 1024), blk, 0, stream>>>(
      x, xb, n0, w_qkv, wqkvb, n1, w_proj, wprojb, n2);

  // 1) qkv GEMM with Q-scale / K / V-transpose epilogue
  gemm_qkv<<<dim3(NQKV / 128, M / 128), blk, 0, stream>>>(
      xb, wqkvb, Qb, Kb, Vt, M, NQKV, C);
  // 2) flash attention: 256T blocks, grid 768 (3 blocks/CU, 12 waves/CU)
  attn_flash<<<dim3(4 * 12 * 16), blk, 0, stream>>>(Qb, Kb, Vt, attn);
  // 3) out = attn @ w_proj^T + b  (fp32 out)
  gemm_proj<<<dim3(C / 128, M / 128), blk, 0, stream>>>(
      attn, wprojb, b_proj, out, M, C, C);
}